// Round 10
// baseline (302.601 us; speedup 1.0000x reference)
//
#include <hip/hip_runtime.h>
#include <stdint.h>

#define N_ROWS 131072
#define DIM 64
#define K_CODES 1024

typedef __attribute__((ext_vector_type(8))) short short8;
typedef __attribute__((ext_vector_type(4))) float float4v;
typedef __attribute__((ext_vector_type(4))) uint32_t u32x4;

#define LOG2E 1.4426950408889634f
#define LOG2_LN2 -0.5287663729448977f   // log2(ln 2)

// Tile image layout (halves): cbhi[32][72] @0 (nsc[code] as f32 in halves 64-65 of each row),
// cblo[32][72] @2304, cbT[64][32] @4608 XOR-swizzled. Tile = 6656 halves = 13312 B.
#define TILE_B 13312

__device__ __forceinline__ uint32_t cvt_pk_bf16(float lo, float hi) {
    uint32_t r;
    asm("v_cvt_pk_bf16_f32 %0, %1, %2" : "=v"(r) : "v"(lo), "v"(hi));
    return r;
}
// lo-limb pair: residuals of (fe,fo) against their packed-bf16 word h, repacked to bf16
__device__ __forceinline__ uint32_t lo_pack(float fe, float fo, uint32_t h) {
    float le = fe - __uint_as_float(h << 16);
    float lo_ = fo - __uint_as_float(h & 0xffff0000u);
    return cvt_pk_bf16(le, lo_);
}
__device__ __forceinline__ float exp2_fast(float x) {   // D = 2^x
    float r; asm("v_exp_f32 %0, %1" : "=v"(r) : "v"(x)); return r;
}
__device__ __forceinline__ float log2_fast(float x) {   // D = log2(x)
    float r; asm("v_log_f32 %0, %1" : "=v"(r) : "v"(x)); return r;
}

// async global->LDS DMA, 16B/lane; LDS dest must be wave-uniform base (+lane*16 implicit)
__device__ __forceinline__ void dma16(const void* g, void* l) {
    __builtin_amdgcn_global_load_lds(
        (const __attribute__((address_space(1))) uint32_t*)g,
        (__attribute__((address_space(3))) uint32_t*)l,
        16, 0, 0);
}

template<int V> struct IC { static constexpr int v = V; };

// ---------------- kernel 1: nsc[k] -> cbhi row pad of the image ----------------
// nsc = -invT*log2e*||c_k||^2 + log2(log2e); stored at img + tile*TILE_B + code*144 + 128.
__global__ __launch_bounds__(256) void nscale_kernel(const float* __restrict__ cb,
                                                     const float* __restrict__ temp,
                                                     char* __restrict__ img) {
    int k = blockIdx.x * 256 + threadIdx.x;
    if (k < K_CODES) {
        const float invT = 1.0f / temp[0];
        const float* r = cb + k * DIM;
        float s = 0.f;
        #pragma unroll
        for (int j = 0; j < DIM; ++j) s = fmaf(r[j], r[j], s);
        const int tile = k >> 5, code = k & 31;
        *(float*)(img + (size_t)tile * TILE_B + code * 144 + 128) =
            fmaf(s, -invT * LOG2E, -LOG2_LN2);
    }
}

// ---------------- kernel 1b: codebook LDS-image, once ----------------
// cbhi/cblo hold cb * (invT*log2e) split-bf16 (GEMM1 -> S pre-scaled);
// cbT holds UNSCALED bf16 cb, [64][32] halves with 16B-slot XOR swizzle:
// element (row, c) at half-index row*32 + (((c>>3) ^ (row&3))<<3) + (c&7).
// cbT cols permuted: code i<16 -> 2i, i>=16 -> 2(i-16)+1.
__global__ __launch_bounds__(256) void cbimg_kernel(const float* __restrict__ cb,
                                                    const float* __restrict__ temp,
                                                    uint16_t* __restrict__ img) {
    const int tile = blockIdx.x, tid = threadIdx.x;
    const int code = tid & 31, db = (tid >> 5) * 8;
    const int k = tile * 32 + code;
    const float sc = (1.0f / temp[0]) * LOG2E;
    const float4* src = reinterpret_cast<const float4*>(cb + (size_t)k * DIM + db);
    const float4 a = src[0], b = src[1];
    // unscaled packs for cbT
    uint32_t h0 = cvt_pk_bf16(a.x, a.y), h1 = cvt_pk_bf16(a.z, a.w);
    uint32_t h2 = cvt_pk_bf16(b.x, b.y), h3 = cvt_pk_bf16(b.z, b.w);
    // scaled hi/lo for GEMM1
    const float sax = a.x*sc, say = a.y*sc, saz = a.z*sc, saw = a.w*sc;
    const float sbx = b.x*sc, sby = b.y*sc, sbz = b.z*sc, sbw = b.w*sc;
    uint32_t g0 = cvt_pk_bf16(sax, say), g1 = cvt_pk_bf16(saz, saw);
    uint32_t g2 = cvt_pk_bf16(sbx, sby), g3 = cvt_pk_bf16(sbz, sbw);
    u32x4 hv = {g0, g1, g2, g3};
    u32x4 lv = { lo_pack(sax,say,g0), lo_pack(saz,saw,g1),
                 lo_pack(sbx,sby,g2), lo_pack(sbz,sbw,g3) };
    uint16_t* t = img + (size_t)tile * (TILE_B / 2);
    *(u32x4*)&t[code*72 + db]        = hv;
    *(u32x4*)&t[2304 + code*72 + db] = lv;
    const int pc = ((code & 15) << 1) | (code >> 4);
    const uint16_t hh[8] = {
        (uint16_t)h0, (uint16_t)(h0 >> 16), (uint16_t)h1, (uint16_t)(h1 >> 16),
        (uint16_t)h2, (uint16_t)(h2 >> 16), (uint16_t)h3, (uint16_t)(h3 >> 16) };
    #pragma unroll
    for (int e = 0; e < 8; ++e) {
        const int row = db + e;
        t[4608 + row*32 + (((pc >> 3) ^ (row & 3)) << 3) + (pc & 7)] = hh[e];
    }
}

// ---------------- threefry2x32, 4-wide lockstep (JAX-compatible, key = (0,42)) ----------------
__device__ __forceinline__ uint32_t rotl32(uint32_t x, uint32_t r) {
    return __builtin_amdgcn_alignbit(x, x, 32u - r);   // 1-inst rotate
}
__device__ __forceinline__ void tf_round4(uint32_t x0[4], uint32_t x1[4], uint32_t r) {
    #pragma unroll
    for (int i = 0; i < 4; ++i) { x0[i] += x1[i]; x1[i] = rotl32(x1[i], r); x1[i] ^= x0[i]; }
}
// counters: c0[i], c1[i] = c0[i] + 2^26 (JAX iota-split pairing)
__device__ __forceinline__ void threefry4w_k42(const uint32_t c0[4],
                                               uint32_t o0[4], uint32_t o1[4]) {
    const uint32_t ks1 = 42u, ks2 = 0x1BD11BDAu ^ 42u;
    uint32_t x0[4], x1[4];
    #pragma unroll
    for (int i = 0; i < 4; ++i) { x0[i] = c0[i]; x1[i] = c0[i] + (1u<<26) + ks1; }
    tf_round4(x0,x1,13); tf_round4(x0,x1,15); tf_round4(x0,x1,26); tf_round4(x0,x1,6);
    #pragma unroll
    for (int i = 0; i < 4; ++i) { x0[i] += ks1; x1[i] += ks2 + 1u; }
    tf_round4(x0,x1,17); tf_round4(x0,x1,29); tf_round4(x0,x1,16); tf_round4(x0,x1,24);
    #pragma unroll
    for (int i = 0; i < 4; ++i) { x0[i] += ks2; x1[i] += 2u; }
    tf_round4(x0,x1,13); tf_round4(x0,x1,15); tf_round4(x0,x1,26); tf_round4(x0,x1,6);
    #pragma unroll
    for (int i = 0; i < 4; ++i) { x1[i] += ks1 + 3u; }
    tf_round4(x0,x1,17); tf_round4(x0,x1,29); tf_round4(x0,x1,16); tf_round4(x0,x1,24);
    #pragma unroll
    for (int i = 0; i < 4; ++i) { x0[i] += ks1; x1[i] += ks2 + 4u; }
    tf_round4(x0,x1,13); tf_round4(x0,x1,15); tf_round4(x0,x1,26); tf_round4(x0,x1,6);
    #pragma unroll
    for (int i = 0; i < 4; ++i) { o0[i] = x0[i] + ks2; o1[i] = x1[i] + 5u; }
}

// l = log2(u), u in [0,1) from mantissa bits. (bits>>9)|0x3f800000 == v_alignbit(0x7F, bits, 9).
// No tiny-clamp: u==0 -> l=-inf -> rcp(-l)=+0 -> p=0 (~16 samples in 2^27; << bf16-p error).
__device__ __forceinline__ float gumbel_l(uint32_t bits) {
    uint32_t fb = __builtin_amdgcn_alignbit(0x7Fu, bits, 9u);
    return log2_fast(__uint_as_float(fb) - 1.0f);
}

// ---------------- kernel 2: fused MFMA quantizer (8-wave blocks) ----------------
// LDS arena (36864 B): buf0 @0 (13312), buf1 @13312 (13312), pbuf @26624 (10240).
// waves_per_eu(4,4): exact 4-wave/EU bucket -> 128-VGPR budget so the allocator
// HOISTS loop-invariants instead of rematerializing at the 64-VGPR bucket.
// Epoch A overlay (dead before first DMA): xhi[8][16][72] @0, xlo @18432.
// z' = 2*S + nsc  (S pre-scaled by invT*log2e; nsc = -invT*log2e*||c||^2 + log2(log2e)).
// T=1: p = 2^z' * rcp(-l), no online max needed.
template<bool T1>
__device__ __forceinline__ void quant_body(
    const float* __restrict__ x, const uint16_t* __restrict__ img,
    const float* __restrict__ cb, const float invT,
    float* __restrict__ out_emb, float* __restrict__ out_ids, char* smem)
{
    uint16_t* const xhiP  = (uint16_t*)smem;           // [8][16][72]
    uint16_t* const xloP  = (uint16_t*)(smem + 18432); // [8][16][72]
    uint16_t* const pbufP = (uint16_t*)(smem + 26624); // [8][16][40]

    const int tid  = threadIdx.x;
    const int wave = tid >> 6, lane = tid & 63, quad = lane >> 4, col = lane & 15;
    const int rowbase = blockIdx.x * 64 + wave * 8;

    // ---- epoch A: stage X tile (bf16 hi + lo residual); 512 threads -> 128 rows ----
    {
        const int s = tid >> 2, w = s >> 4, t = s & 15, dq = tid & 3;
        const int row = blockIdx.x * 64 + w * 8 + (t >> 1) + ((t & 1) << 16);
        const float4* src = reinterpret_cast<const float4*>(x + (size_t)row * DIM + dq * 16);
        float4 f0 = src[0], f1 = src[1], f2 = src[2], f3 = src[3];
        u32x4 hA = { cvt_pk_bf16(f0.x,f0.y), cvt_pk_bf16(f0.z,f0.w),
                     cvt_pk_bf16(f1.x,f1.y), cvt_pk_bf16(f1.z,f1.w) };
        u32x4 hB = { cvt_pk_bf16(f2.x,f2.y), cvt_pk_bf16(f2.z,f2.w),
                     cvt_pk_bf16(f3.x,f3.y), cvt_pk_bf16(f3.z,f3.w) };
        u32x4 lA = { lo_pack(f0.x,f0.y,hA[0]), lo_pack(f0.z,f0.w,hA[1]),
                     lo_pack(f1.x,f1.y,hA[2]), lo_pack(f1.z,f1.w,hA[3]) };
        u32x4 lB = { lo_pack(f2.x,f2.y,hB[0]), lo_pack(f2.z,f2.w,hB[1]),
                     lo_pack(f3.x,f3.y,hB[2]), lo_pack(f3.z,f3.w,hB[3]) };
        uint16_t* dsth = &xhiP[(w*16 + t)*72 + dq*16];
        uint16_t* dstl = &xloP[(w*16 + t)*72 + dq*16];
        *(u32x4*)(dsth)     = hA;
        *(u32x4*)(dsth + 8) = hB;
        *(u32x4*)(dstl)     = lA;
        *(u32x4*)(dstl + 8) = lB;
    }
    __syncthreads();

    // A-frags cached in VGPRs for the whole kernel: A[m=col][k=quad*8+e]
    const int arb = (wave*16 + col)*72;
    const short8 ahi0 = *(const short8*)&xhiP[arb + quad*8];
    const short8 ahi1 = *(const short8*)&xhiP[arb + 32 + quad*8];
    const short8 alo0 = *(const short8*)&xloP[arb + quad*8];
    const short8 alo1 = *(const short8*)&xloP[arb + 32 + quad*8];
    __syncthreads();   // all waves done reading xhi/xlo (drained) before DMA overwrites

    // ---- DMA plumbing: 13 x 1KiB chunks/tile over 8 waves ----
    const char* gdma = (const char*)img + (size_t)lane * 16;
    auto dma_tile = [&](int tile, int bofs) {
        const char* s = gdma + (size_t)tile * TILE_B;
        char* d = smem + bofs;
        dma16(s + (size_t)wave*1024, d + wave*1024);
        if (wave < 5) dma16(s + (size_t)(wave+8)*1024, d + (wave+8)*1024);
    };
    dma_tile(0, 0);
    __syncthreads();   // vmcnt(0) drain inside -> tile 0 resident

    // threefry counter base: c(row n0, code kb+col) = base_c0 + kb
    const uint32_t base_c0 = (uint32_t)(rowbase + 2*quad) * 1024u + (uint32_t)col;

    float m[4]  = {-1e30f, -1e30f, -1e30f, -1e30f};     // !T1 only (DCE'd for T1)
    float Zp[4] = {0.f, 0.f, 0.f, 0.f};
    float4v e0 = {0,0,0,0}, e1 = {0,0,0,0}, e2 = {0,0,0,0}, e3 = {0,0,0,0};
    // top-2 in z'-units (track MAX); strict > keeps lowest k
    float zt[4] = {-3.4e38f,-3.4e38f,-3.4e38f,-3.4e38f};
    float zs[4] = {-3.4e38f,-3.4e38f,-3.4e38f,-3.4e38f};
    int   kt[4] = {0,0,0,0}, ks[4] = {0,0,0,0};

    auto body = [&](int blk, auto B) {
        constexpr int BOF = decltype(B)::v;
        const uint16_t* cbhi = (const uint16_t*)(smem + BOF);
        const uint16_t* cblo = cbhi + 2304;
        const uint16_t* cbT  = cbhi + 4608;            // [64][32] XOR-swizzled
        const int kb  = blk * 32;
        const int kc0 = kb + col, kc1 = kc0 + 16;

        if (blk + 1 < 32) dma_tile(blk + 1, BOF ^ TILE_B);
        // nsc rides in cbhi row padding (halves 64-65 of each row)
        const float nsc0 = *(const float*)&cbhi[col*72 + 64];
        const float nsc1 = *(const float*)&cbhi[(16 + col)*72 + 64];

        // ---- gumbels: 4-wide lockstep threefry -> l = log2(u) per sample ----
        float l0c[4], l1c[4];
        {
            const uint32_t cA = base_c0 + (uint32_t)kb;
            const uint32_t c0s[4] = {cA, cA + 1024u, cA + 16u, cA + 1040u};
            uint32_t o0[4], o1[4];
            threefry4w_k42(c0s, o0, o1);
            float l[8];
            #pragma unroll
            for (int i = 0; i < 4; ++i) { l[2*i] = gumbel_l(o0[i]); l[2*i+1] = gumbel_l(o1[i]); }
            #pragma unroll
            for (int j = 0; j < 4; ++j) {
                if (T1) { l0c[j] = l[j]; l1c[j] = l[4+j]; }
                else {   // gumbel in log2-softmax units: -invT*(log2(-l) + log2(ln2))
                    l0c[j] = -invT * (log2_fast(-l[j])   + LOG2_LN2);
                    l1c[j] = -invT * (log2_fast(-l[4+j]) + LOG2_LN2);
                }
            }
        }

        // ---- GEMM1: S = (invT*log2e) X . CB^T (split-bf16, 12 MFMA) ----
        float4v S0 = {0,0,0,0}, S1 = {0,0,0,0};
        {
            const int rb0 = col*72;
            const short8 bh0 = *(const short8*)&cbhi[rb0 + quad*8];
            const short8 bh1 = *(const short8*)&cbhi[rb0 + 32 + quad*8];
            const short8 bl0 = *(const short8*)&cblo[rb0 + quad*8];
            const short8 bl1 = *(const short8*)&cblo[rb0 + 32 + quad*8];
            S0 = __builtin_amdgcn_mfma_f32_16x16x32_bf16(ahi0, bh0, S0, 0,0,0);
            S0 = __builtin_amdgcn_mfma_f32_16x16x32_bf16(ahi1, bh1, S0, 0,0,0);
            S0 = __builtin_amdgcn_mfma_f32_16x16x32_bf16(ahi0, bl0, S0, 0,0,0);
            S0 = __builtin_amdgcn_mfma_f32_16x16x32_bf16(ahi1, bl1, S0, 0,0,0);
            S0 = __builtin_amdgcn_mfma_f32_16x16x32_bf16(alo0, bh0, S0, 0,0,0);
            S0 = __builtin_amdgcn_mfma_f32_16x16x32_bf16(alo1, bh1, S0, 0,0,0);
        }
        {
            const int rb1 = (16 + col)*72;
            const short8 bh0 = *(const short8*)&cbhi[rb1 + quad*8];
            const short8 bh1 = *(const short8*)&cbhi[rb1 + 32 + quad*8];
            const short8 bl0 = *(const short8*)&cblo[rb1 + quad*8];
            const short8 bl1 = *(const short8*)&cblo[rb1 + 32 + quad*8];
            S1 = __builtin_amdgcn_mfma_f32_16x16x32_bf16(ahi0, bh0, S1, 0,0,0);
            S1 = __builtin_amdgcn_mfma_f32_16x16x32_bf16(ahi1, bh1, S1, 0,0,0);
            S1 = __builtin_amdgcn_mfma_f32_16x16x32_bf16(ahi0, bl0, S1, 0,0,0);
            S1 = __builtin_amdgcn_mfma_f32_16x16x32_bf16(ahi1, bl1, S1, 0,0,0);
            S1 = __builtin_amdgcn_mfma_f32_16x16x32_bf16(alo0, bh0, S1, 0,0,0);
            S1 = __builtin_amdgcn_mfma_f32_16x16x32_bf16(alo1, bh1, S1, 0,0,0);
        }

        // ---- z' = 2S + nsc + top-2 ----
        float z0v[4], z1v[4];
        #pragma unroll
        for (int j = 0; j < 4; ++j) {
            const float z0 = fmaf(S0[j], 2.0f, nsc0);
            const float z1 = fmaf(S1[j], 2.0f, nsc1);
            {   const bool c1 = z0 > zt[j], c2 = z0 > zs[j];
                const float zsn = __builtin_amdgcn_fmed3f(z0, zt[j], zs[j]);
                ks[j] = c1 ? kt[j] : (c2 ? kc0 : ks[j]);
                kt[j] = c1 ? kc0 : kt[j];
                zt[j] = fmaxf(zt[j], z0);
                zs[j] = zsn; }
            {   const bool c1 = z1 > zt[j], c2 = z1 > zs[j];
                const float zsn = __builtin_amdgcn_fmed3f(z1, zt[j], zs[j]);
                ks[j] = c1 ? kt[j] : (c2 ? kc1 : ks[j]);
                kt[j] = c1 ? kc1 : kt[j];
                zt[j] = fmaxf(zt[j], z1);
                zs[j] = zsn; }
            z0v[j] = z0; z1v[j] = z1;
        }

        if (T1) {
            // ---- p = 2^z' * rcp(-l); |z'| bounded, f32-safe, no online max ----
            #pragma unroll
            for (int j = 0; j < 4; ++j) {
                const float p0 = exp2_fast(z0v[j]) * __builtin_amdgcn_rcpf(-l0c[j]);
                const float p1 = exp2_fast(z1v[j]) * __builtin_amdgcn_rcpf(-l1c[j]);
                Zp[j] += p0 + p1;
                ((uint32_t*)pbufP)[(wave*16 + quad*4 + j)*20 + col] = cvt_pk_bf16(p0, p1);
            }
        } else {
            // ---- general-T: gumbel added, always-rescale online max ----
            float a0[4], a1[4], zm[4];
            #pragma unroll
            for (int j = 0; j < 4; ++j) {
                a0[j] = z0v[j] + l0c[j];
                a1[j] = z1v[j] + l1c[j];
                zm[j] = fmaxf(a0[j], a1[j]);
            }
            float4v av;
            #pragma unroll
            for (int j = 0; j < 4; ++j) {
                float mn = fmaxf(m[j], zm[j]);
                #pragma unroll
                for (int mask = 1; mask < 16; mask <<= 1)
                    mn = fmaxf(mn, __shfl_xor(mn, mask));
                const float al = exp2_fast(m[j] - mn);
                m[j] = mn; Zp[j] *= al; av[j] = al;
            }
            e0 *= av; e1 *= av; e2 *= av; e3 *= av;
            #pragma unroll
            for (int j = 0; j < 4; ++j) {
                const float p0 = exp2_fast(a0[j] - m[j]);
                const float p1 = exp2_fast(a1[j] - m[j]);
                Zp[j] += p0 + p1;
                ((uint32_t*)pbufP)[(wave*16 + quad*4 + j)*20 + col] = cvt_pk_bf16(p0, p1);
            }
        }

        // ---- GEMM2: emb += P . CB (pbuf wave-private; cbT swizzled reads) ----
        const short8 pa = *(const short8*)&pbufP[(wave*16 + col)*40 + quad*8];
        const int ts = (quad ^ (col & 3)) * 8;   // swizzled 16B slot within row
        const short8 bt0 = *(const short8*)&cbT[( 0 + col)*32 + ts];
        const short8 bt1 = *(const short8*)&cbT[(16 + col)*32 + ts];
        const short8 bt2 = *(const short8*)&cbT[(32 + col)*32 + ts];
        const short8 bt3 = *(const short8*)&cbT[(48 + col)*32 + ts];
        e0 = __builtin_amdgcn_mfma_f32_16x16x32_bf16(pa, bt0, e0, 0,0,0);
        e1 = __builtin_amdgcn_mfma_f32_16x16x32_bf16(pa, bt1, e1, 0,0,0);
        e2 = __builtin_amdgcn_mfma_f32_16x16x32_bf16(pa, bt2, e2, 0,0,0);
        e3 = __builtin_amdgcn_mfma_f32_16x16x32_bf16(pa, bt3, e3, 0,0,0);

        __syncthreads();   // drains vmcnt (next-tile DMA done) + lgkm; buffers swap-safe
    };

    for (int blk = 0; blk < 32; blk += 2) {
        body(blk,     IC<0>{});
        body(blk + 1, IC<TILE_B>{});
    }

    // ---- epilogue: reduce Z, merge top-2, f64 refine near-ties, write ----
    #pragma unroll
    for (int mask = 1; mask < 16; mask <<= 1) {
        #pragma unroll
        for (int j = 0; j < 4; ++j) Zp[j] += __shfl_xor(Zp[j], mask);
    }
    #pragma unroll
    for (int mask = 1; mask < 16; mask <<= 1) {
        #pragma unroll
        for (int j = 0; j < 4; ++j) {
            const float ozt = __shfl_xor(zt[j], mask);
            const float ozs = __shfl_xor(zs[j], mask);
            const int   okt = __shfl_xor(kt[j], mask);
            const int   oks = __shfl_xor(ks[j], mask);
            const bool mf = (zt[j] > ozt) || (zt[j] == ozt && kt[j] < okt);
            const float w1 = mf ? zt[j] : ozt;  const int wk1 = mf ? kt[j] : okt;
            const float l1 = mf ? ozt : zt[j];  const int lk1 = mf ? okt : kt[j];
            const float w2 = mf ? zs[j] : ozs;  const int wk2 = mf ? ks[j] : oks;
            const bool s1 = (l1 > w2) || (l1 == w2 && lk1 < wk2);
            zt[j] = w1; kt[j] = wk1;
            zs[j] = s1 ? l1 : w2; ks[j] = s1 ? lk1 : wk2;
        }
    }
    // exact f64 refinement for near-ties (split-bf16 dist err ~1e-6; z'-gap thr 0.015*invT
    // == dist gap ~1.04e-2, matching the proven 1e-2 margin; const shift cancels in gap)
    if (col == 0) {
        #pragma unroll
        for (int j = 0; j < 4; ++j) {
            if (zt[j] - zs[j] < 0.015f * invT) {
                const int t = quad*4 + j;
                const int row = rowbase + (t >> 1) + ((t & 1) << 16);
                const float* xr = x + (size_t)row * DIM;
                const float* cA = cb + (size_t)kt[j] * DIM;
                const float* cB = cb + (size_t)ks[j] * DIM;
                double dA = 0.0, dB = 0.0;     // ||c||^2 - 2 x.c (||x||^2 cancels)
                for (int d = 0; d < DIM; ++d) {
                    const double xv = (double)xr[d];
                    const double av2 = (double)cA[d], bv = (double)cB[d];
                    dA = fma(av2, av2, dA); dA = fma(-2.0*xv, av2, dA);
                    dB = fma(bv,  bv,  dB); dB = fma(-2.0*xv, bv,  dB);
                }
                if (dB < dA || (dB == dA && ks[j] < kt[j])) kt[j] = ks[j];
            }
        }
    }
    #pragma unroll
    for (int j = 0; j < 4; ++j) {
        const int t = quad*4 + j;
        const int row = rowbase + (t >> 1) + ((t & 1) << 16);
        const float rZ = __builtin_amdgcn_rcpf(Zp[j]);
        out_emb[(size_t)row * DIM +      col] = e0[j] * rZ;
        out_emb[(size_t)row * DIM + 16 + col] = e1[j] * rZ;
        out_emb[(size_t)row * DIM + 32 + col] = e2[j] * rZ;
        out_emb[(size_t)row * DIM + 48 + col] = e3[j] * rZ;
        if (col == 0) out_ids[row] = (float)kt[j];
    }
}

__global__ __launch_bounds__(512) __attribute__((amdgpu_waves_per_eu(4, 4)))
void quant_kernel(
    const float* __restrict__ x, const uint16_t* __restrict__ img,
    const float* __restrict__ cb, const float* __restrict__ temp,
    float* __restrict__ out_emb, float* __restrict__ out_ids)
{
    __shared__ __align__(16) char smem[36864];
    const float invT = 1.0f / temp[0];
    if (invT == 1.0f) quant_body<true >(x, img, cb, invT, out_emb, out_ids, smem);
    else              quant_body<false>(x, img, cb, invT, out_emb, out_ids, smem);
}

extern "C" void kernel_launch(void* const* d_in, const int* in_sizes, int n_in,
                              void* d_out, int out_size, void* d_ws, size_t ws_size,
                              hipStream_t stream) {
    const float* x    = (const float*)d_in[0];
    const float* cb   = (const float*)d_in[1];
    const float* temp = (const float*)d_in[2];
    uint16_t* img     = (uint16_t*)d_ws;                  // 32 tiles x 13312 B = 416 KiB
    float* out_emb    = (float*)d_out;
    float* out_ids    = (float*)d_out + (size_t)N_ROWS * DIM;

    nscale_kernel<<<(K_CODES + 255) / 256, 256, 0, stream>>>(cb, temp, (char*)img);
    cbimg_kernel<<<32, 256, 0, stream>>>(cb, temp, img);
    quant_kernel<<<N_ROWS / 128, 512, 0, stream>>>(x, img, cb, temp, out_emb, out_ids);
}

// Round 12
// 298.421 us; speedup vs baseline: 1.0140x; 1.0140x over previous
//
#include <hip/hip_runtime.h>
#include <stdint.h>

#define N_ROWS 131072
#define DIM 64
#define K_CODES 1024

typedef __attribute__((ext_vector_type(8))) short short8;
typedef __attribute__((ext_vector_type(4))) float float4v;
typedef __attribute__((ext_vector_type(4))) uint32_t u32x4;

#define LOG2E 1.4426950408889634f
#define LOG2_LN2 -0.5287663729448977f   // log2(ln 2)

// Tile image layout (halves): cbhi[32][72] @0 (nsc[code] as f32 in halves 64-65 of each row),
// cblo[32][72] @2304, cbT[64][32] @4608 XOR-swizzled. Tile = 6656 halves = 13312 B.
#define TILE_B 13312

__device__ __forceinline__ uint32_t cvt_pk_bf16(float lo, float hi) {
    uint32_t r;
    asm("v_cvt_pk_bf16_f32 %0, %1, %2" : "=v"(r) : "v"(lo), "v"(hi));
    return r;
}
// lo-limb pair: residuals of (fe,fo) against their packed-bf16 word h, repacked to bf16
__device__ __forceinline__ uint32_t lo_pack(float fe, float fo, uint32_t h) {
    float le = fe - __uint_as_float(h << 16);
    float lo_ = fo - __uint_as_float(h & 0xffff0000u);
    return cvt_pk_bf16(le, lo_);
}
__device__ __forceinline__ float exp2_fast(float x) {   // D = 2^x
    float r; asm("v_exp_f32 %0, %1" : "=v"(r) : "v"(x)); return r;
}
__device__ __forceinline__ float log2_fast(float x) {   // D = log2(x)
    float r; asm("v_log_f32 %0, %1" : "=v"(r) : "v"(x)); return r;
}

// async global->LDS DMA, 16B/lane; LDS dest must be wave-uniform base (+lane*16 implicit)
__device__ __forceinline__ void dma16(const void* g, void* l) {
    __builtin_amdgcn_global_load_lds(
        (const __attribute__((address_space(1))) uint32_t*)g,
        (__attribute__((address_space(3))) uint32_t*)l,
        16, 0, 0);
}

template<int V> struct IC { static constexpr int v = V; };

// ---------------- kernel 1 (FUSED): codebook LDS-image + nsc, once ----------------
// cbhi/cblo hold cb * (invT*log2e) split-bf16 (GEMM1 -> S pre-scaled);
// cbT holds UNSCALED bf16 cb, [64][32] halves with 16B-slot XOR swizzle:
// element (row, c) at half-index row*32 + (((c>>3) ^ (row&3))<<3) + (c&7).
// cbT cols permuted: code i<16 -> 2i, i>=16 -> 2(i-16)+1.
// nsc[code] = -invT*log2e*||c||^2 + log2(log2e), written into cbhi row pad
// (bytes 128-131 of each 144 B row) via an LDS partial-sum reduction.
__global__ __launch_bounds__(256) void cbimg_kernel(const float* __restrict__ cb,
                                                    const float* __restrict__ temp,
                                                    uint16_t* __restrict__ img) {
    __shared__ float part[256];   // [seg=db/8][code]
    const int tile = blockIdx.x, tid = threadIdx.x;
    const int code = tid & 31, db = (tid >> 5) * 8;
    const int k = tile * 32 + code;
    const float invT = 1.0f / temp[0];
    const float sc = invT * LOG2E;
    const float4* src = reinterpret_cast<const float4*>(cb + (size_t)k * DIM + db);
    const float4 a = src[0], b = src[1];
    // partial ||c||^2 from unscaled elements
    float ps = a.x*a.x;
    ps = fmaf(a.y, a.y, ps); ps = fmaf(a.z, a.z, ps); ps = fmaf(a.w, a.w, ps);
    ps = fmaf(b.x, b.x, ps); ps = fmaf(b.y, b.y, ps); ps = fmaf(b.z, b.z, ps);
    ps = fmaf(b.w, b.w, ps);
    part[(db >> 3) * 32 + code] = ps;
    // unscaled packs for cbT
    uint32_t h0 = cvt_pk_bf16(a.x, a.y), h1 = cvt_pk_bf16(a.z, a.w);
    uint32_t h2 = cvt_pk_bf16(b.x, b.y), h3 = cvt_pk_bf16(b.z, b.w);
    // scaled hi/lo for GEMM1
    const float sax = a.x*sc, say = a.y*sc, saz = a.z*sc, saw = a.w*sc;
    const float sbx = b.x*sc, sby = b.y*sc, sbz = b.z*sc, sbw = b.w*sc;
    uint32_t g0 = cvt_pk_bf16(sax, say), g1 = cvt_pk_bf16(saz, saw);
    uint32_t g2 = cvt_pk_bf16(sbx, sby), g3 = cvt_pk_bf16(sbz, sbw);
    u32x4 hv = {g0, g1, g2, g3};
    u32x4 lv = { lo_pack(sax,say,g0), lo_pack(saz,saw,g1),
                 lo_pack(sbx,sby,g2), lo_pack(sbz,sbw,g3) };
    uint16_t* t = img + (size_t)tile * (TILE_B / 2);
    *(u32x4*)&t[code*72 + db]        = hv;
    *(u32x4*)&t[2304 + code*72 + db] = lv;
    const int pc = ((code & 15) << 1) | (code >> 4);
    const uint16_t hh[8] = {
        (uint16_t)h0, (uint16_t)(h0 >> 16), (uint16_t)h1, (uint16_t)(h1 >> 16),
        (uint16_t)h2, (uint16_t)(h2 >> 16), (uint16_t)h3, (uint16_t)(h3 >> 16) };
    #pragma unroll
    for (int e = 0; e < 8; ++e) {
        const int row = db + e;
        t[4608 + row*32 + (((pc >> 3) ^ (row & 3)) << 3) + (pc & 7)] = hh[e];
    }
    __syncthreads();
    if (tid < 32) {
        float s = part[tid];
        #pragma unroll
        for (int i = 1; i < 8; ++i) s += part[i*32 + tid];
        *(float*)((char*)t + tid * 144 + 128) = fmaf(s, -sc, -LOG2_LN2);
    }
}

// ---------------- threefry2x32, 4-wide lockstep (JAX-compatible, key = (0,42)) ----------------
__device__ __forceinline__ uint32_t rotl32(uint32_t x, uint32_t r) {
    return __builtin_amdgcn_alignbit(x, x, 32u - r);   // 1-inst rotate
}
__device__ __forceinline__ void tf_round4(uint32_t x0[4], uint32_t x1[4], uint32_t r) {
    #pragma unroll
    for (int i = 0; i < 4; ++i) { x0[i] += x1[i]; x1[i] = rotl32(x1[i], r); x1[i] ^= x0[i]; }
}
// counters: c0[i], c1[i] = c0[i] + 2^26 (JAX iota-split pairing)
__device__ __forceinline__ void threefry4w_k42(const uint32_t c0[4],
                                               uint32_t o0[4], uint32_t o1[4]) {
    const uint32_t ks1 = 42u, ks2 = 0x1BD11BDAu ^ 42u;
    uint32_t x0[4], x1[4];
    #pragma unroll
    for (int i = 0; i < 4; ++i) { x0[i] = c0[i]; x1[i] = c0[i] + (1u<<26) + ks1; }
    tf_round4(x0,x1,13); tf_round4(x0,x1,15); tf_round4(x0,x1,26); tf_round4(x0,x1,6);
    #pragma unroll
    for (int i = 0; i < 4; ++i) { x0[i] += ks1; x1[i] += ks2 + 1u; }
    tf_round4(x0,x1,17); tf_round4(x0,x1,29); tf_round4(x0,x1,16); tf_round4(x0,x1,24);
    #pragma unroll
    for (int i = 0; i < 4; ++i) { x0[i] += ks2; x1[i] += 2u; }
    tf_round4(x0,x1,13); tf_round4(x0,x1,15); tf_round4(x0,x1,26); tf_round4(x0,x1,6);
    #pragma unroll
    for (int i = 0; i < 4; ++i) { x1[i] += ks1 + 3u; }
    tf_round4(x0,x1,17); tf_round4(x0,x1,29); tf_round4(x0,x1,16); tf_round4(x0,x1,24);
    #pragma unroll
    for (int i = 0; i < 4; ++i) { x0[i] += ks1; x1[i] += ks2 + 4u; }
    tf_round4(x0,x1,13); tf_round4(x0,x1,15); tf_round4(x0,x1,26); tf_round4(x0,x1,6);
    #pragma unroll
    for (int i = 0; i < 4; ++i) { o0[i] = x0[i] + ks2; o1[i] = x1[i] + 5u; }
}

// l = log2(u), u in [0,1) from mantissa bits. (bits>>9)|0x3f800000 == v_alignbit(0x7F, bits, 9).
// No tiny-clamp: u==0 -> l=-inf -> rcp(-l)=+0 -> p=0 (~16 samples in 2^27; << bf16-p error).
__device__ __forceinline__ float gumbel_l(uint32_t bits) {
    uint32_t fb = __builtin_amdgcn_alignbit(0x7Fu, bits, 9u);
    return log2_fast(__uint_as_float(fb) - 1.0f);
}

// ---------------- kernel 2: fused MFMA quantizer (8-wave blocks) ----------------
// LDS arena (36864 B): buf0 @0 (13312), buf1 @13312 (13312), pbuf @26624 (10240).
// Epoch A overlay (dead before first DMA): xhi[8][16][72] @0, xlo @18432.
// z' = 2*S + nsc  (S pre-scaled by invT*log2e; nsc = -invT*log2e*||c||^2 + log2(log2e)).
// T=1: p = 2^z' * rcp(-l), no online max needed.
template<bool T1>
__device__ __forceinline__ void quant_body(
    const float* __restrict__ x, const uint16_t* __restrict__ img,
    const float* __restrict__ cb, const float invT,
    float* __restrict__ out_emb, float* __restrict__ out_ids, char* smem)
{
    uint16_t* const xhiP  = (uint16_t*)smem;           // [8][16][72]
    uint16_t* const xloP  = (uint16_t*)(smem + 18432); // [8][16][72]
    uint16_t* const pbufP = (uint16_t*)(smem + 26624); // [8][16][40]

    const int tid  = threadIdx.x;
    const int wave = tid >> 6, lane = tid & 63, quad = lane >> 4, col = lane & 15;
    const int rowbase = blockIdx.x * 64 + wave * 8;

    // ---- epoch A: stage X tile (bf16 hi + lo residual); 512 threads -> 128 rows ----
    {
        const int s = tid >> 2, w = s >> 4, t = s & 15, dq = tid & 3;
        const int row = blockIdx.x * 64 + w * 8 + (t >> 1) + ((t & 1) << 16);
        const float4* src = reinterpret_cast<const float4*>(x + (size_t)row * DIM + dq * 16);
        float4 f0 = src[0], f1 = src[1], f2 = src[2], f3 = src[3];
        u32x4 hA = { cvt_pk_bf16(f0.x,f0.y), cvt_pk_bf16(f0.z,f0.w),
                     cvt_pk_bf16(f1.x,f1.y), cvt_pk_bf16(f1.z,f1.w) };
        u32x4 hB = { cvt_pk_bf16(f2.x,f2.y), cvt_pk_bf16(f2.z,f2.w),
                     cvt_pk_bf16(f3.x,f3.y), cvt_pk_bf16(f3.z,f3.w) };
        u32x4 lA = { lo_pack(f0.x,f0.y,hA[0]), lo_pack(f0.z,f0.w,hA[1]),
                     lo_pack(f1.x,f1.y,hA[2]), lo_pack(f1.z,f1.w,hA[3]) };
        u32x4 lB = { lo_pack(f2.x,f2.y,hB[0]), lo_pack(f2.z,f2.w,hB[1]),
                     lo_pack(f3.x,f3.y,hB[2]), lo_pack(f3.z,f3.w,hB[3]) };
        uint16_t* dsth = &xhiP[(w*16 + t)*72 + dq*16];
        uint16_t* dstl = &xloP[(w*16 + t)*72 + dq*16];
        *(u32x4*)(dsth)     = hA;
        *(u32x4*)(dsth + 8) = hB;
        *(u32x4*)(dstl)     = lA;
        *(u32x4*)(dstl + 8) = lB;
    }
    __syncthreads();

    // A-frags cached in VGPRs for the whole kernel: A[m=col][k=quad*8+e]
    const int arb = (wave*16 + col)*72;
    const short8 ahi0 = *(const short8*)&xhiP[arb + quad*8];
    const short8 ahi1 = *(const short8*)&xhiP[arb + 32 + quad*8];
    const short8 alo0 = *(const short8*)&xloP[arb + quad*8];
    const short8 alo1 = *(const short8*)&xloP[arb + 32 + quad*8];
    __syncthreads();   // all waves done reading xhi/xlo (drained) before DMA overwrites

    // ---- DMA plumbing: 13 x 1KiB chunks/tile over 8 waves ----
    const char* gdma = (const char*)img + (size_t)lane * 16;
    auto dma_tile = [&](int tile, int bofs) {
        const char* s = gdma + (size_t)tile * TILE_B;
        char* d = smem + bofs;
        dma16(s + (size_t)wave*1024, d + wave*1024);
        if (wave < 5) dma16(s + (size_t)(wave+8)*1024, d + (wave+8)*1024);
    };
    dma_tile(0, 0);
    __syncthreads();   // vmcnt(0) drain inside -> tile 0 resident

    // threefry counter base: c(row n0, code kb+col) = base_c0 + kb
    const uint32_t base_c0 = (uint32_t)(rowbase + 2*quad) * 1024u + (uint32_t)col;

    float m[4]  = {-1e30f, -1e30f, -1e30f, -1e30f};     // !T1 only (DCE'd for T1)
    float Zp[4] = {0.f, 0.f, 0.f, 0.f};
    float4v e0 = {0,0,0,0}, e1 = {0,0,0,0}, e2 = {0,0,0,0}, e3 = {0,0,0,0};
    // top-2 in z'-units (track MAX); strict > keeps lowest k
    float zt[4] = {-3.4e38f,-3.4e38f,-3.4e38f,-3.4e38f};
    float zs[4] = {-3.4e38f,-3.4e38f,-3.4e38f,-3.4e38f};
    int   kt[4] = {0,0,0,0}, ks[4] = {0,0,0,0};

    auto body = [&](int blk, auto B) {
        constexpr int BOF = decltype(B)::v;
        const uint16_t* cbhi = (const uint16_t*)(smem + BOF);
        const uint16_t* cblo = cbhi + 2304;
        const uint16_t* cbT  = cbhi + 4608;            // [64][32] XOR-swizzled
        const int kb  = blk * 32;
        const int kc0 = kb + col, kc1 = kc0 + 16;

        if (blk + 1 < 32) dma_tile(blk + 1, BOF ^ TILE_B);
        // nsc rides in cbhi row padding (halves 64-65 of each row)
        const float nsc0 = *(const float*)&cbhi[col*72 + 64];
        const float nsc1 = *(const float*)&cbhi[(16 + col)*72 + 64];

        // ---- gumbels: 4-wide lockstep threefry -> l = log2(u) per sample ----
        float l0c[4], l1c[4];
        {
            const uint32_t cA = base_c0 + (uint32_t)kb;
            const uint32_t c0s[4] = {cA, cA + 1024u, cA + 16u, cA + 1040u};
            uint32_t o0[4], o1[4];
            threefry4w_k42(c0s, o0, o1);
            float l[8];
            #pragma unroll
            for (int i = 0; i < 4; ++i) { l[2*i] = gumbel_l(o0[i]); l[2*i+1] = gumbel_l(o1[i]); }
            #pragma unroll
            for (int j = 0; j < 4; ++j) {
                if (T1) { l0c[j] = l[j]; l1c[j] = l[4+j]; }
                else {   // gumbel in log2-softmax units: -invT*(log2(-l) + log2(ln2))
                    l0c[j] = -invT * (log2_fast(-l[j])   + LOG2_LN2);
                    l1c[j] = -invT * (log2_fast(-l[4+j]) + LOG2_LN2);
                }
            }
        }

        // ---- GEMM1: S = (invT*log2e) X . CB^T (split-bf16, 12 MFMA) ----
        float4v S0 = {0,0,0,0}, S1 = {0,0,0,0};
        {
            const int rb0 = col*72;
            const short8 bh0 = *(const short8*)&cbhi[rb0 + quad*8];
            const short8 bh1 = *(const short8*)&cbhi[rb0 + 32 + quad*8];
            const short8 bl0 = *(const short8*)&cblo[rb0 + quad*8];
            const short8 bl1 = *(const short8*)&cblo[rb0 + 32 + quad*8];
            S0 = __builtin_amdgcn_mfma_f32_16x16x32_bf16(ahi0, bh0, S0, 0,0,0);
            S0 = __builtin_amdgcn_mfma_f32_16x16x32_bf16(ahi1, bh1, S0, 0,0,0);
            S0 = __builtin_amdgcn_mfma_f32_16x16x32_bf16(ahi0, bl0, S0, 0,0,0);
            S0 = __builtin_amdgcn_mfma_f32_16x16x32_bf16(ahi1, bl1, S0, 0,0,0);
            S0 = __builtin_amdgcn_mfma_f32_16x16x32_bf16(alo0, bh0, S0, 0,0,0);
            S0 = __builtin_amdgcn_mfma_f32_16x16x32_bf16(alo1, bh1, S0, 0,0,0);
        }
        {
            const int rb1 = (16 + col)*72;
            const short8 bh0 = *(const short8*)&cbhi[rb1 + quad*8];
            const short8 bh1 = *(const short8*)&cbhi[rb1 + 32 + quad*8];
            const short8 bl0 = *(const short8*)&cblo[rb1 + quad*8];
            const short8 bl1 = *(const short8*)&cblo[rb1 + 32 + quad*8];
            S1 = __builtin_amdgcn_mfma_f32_16x16x32_bf16(ahi0, bh0, S1, 0,0,0);
            S1 = __builtin_amdgcn_mfma_f32_16x16x32_bf16(ahi1, bh1, S1, 0,0,0);
            S1 = __builtin_amdgcn_mfma_f32_16x16x32_bf16(ahi0, bl0, S1, 0,0,0);
            S1 = __builtin_amdgcn_mfma_f32_16x16x32_bf16(ahi1, bl1, S1, 0,0,0);
            S1 = __builtin_amdgcn_mfma_f32_16x16x32_bf16(alo0, bh0, S1, 0,0,0);
            S1 = __builtin_amdgcn_mfma_f32_16x16x32_bf16(alo1, bh1, S1, 0,0,0);
        }

        // ---- z' = 2S + nsc + top-2 ----
        float z0v[4], z1v[4];
        #pragma unroll
        for (int j = 0; j < 4; ++j) {
            const float z0 = fmaf(S0[j], 2.0f, nsc0);
            const float z1 = fmaf(S1[j], 2.0f, nsc1);
            {   const bool c1 = z0 > zt[j], c2 = z0 > zs[j];
                const float zsn = __builtin_amdgcn_fmed3f(z0, zt[j], zs[j]);
                ks[j] = c1 ? kt[j] : (c2 ? kc0 : ks[j]);
                kt[j] = c1 ? kc0 : kt[j];
                zt[j] = fmaxf(zt[j], z0);
                zs[j] = zsn; }
            {   const bool c1 = z1 > zt[j], c2 = z1 > zs[j];
                const float zsn = __builtin_amdgcn_fmed3f(z1, zt[j], zs[j]);
                ks[j] = c1 ? kt[j] : (c2 ? kc1 : ks[j]);
                kt[j] = c1 ? kc1 : kt[j];
                zt[j] = fmaxf(zt[j], z1);
                zs[j] = zsn; }
            z0v[j] = z0; z1v[j] = z1;
        }

        if (T1) {
            // ---- p = 2^z' * rcp(-l); |z'| bounded, f32-safe, no online max ----
            #pragma unroll
            for (int j = 0; j < 4; ++j) {
                const float p0 = exp2_fast(z0v[j]) * __builtin_amdgcn_rcpf(-l0c[j]);
                const float p1 = exp2_fast(z1v[j]) * __builtin_amdgcn_rcpf(-l1c[j]);
                Zp[j] += p0 + p1;
                ((uint32_t*)pbufP)[(wave*16 + quad*4 + j)*20 + col] = cvt_pk_bf16(p0, p1);
            }
        } else {
            // ---- general-T: gumbel added, always-rescale online max ----
            float a0[4], a1[4], zm[4];
            #pragma unroll
            for (int j = 0; j < 4; ++j) {
                a0[j] = z0v[j] + l0c[j];
                a1[j] = z1v[j] + l1c[j];
                zm[j] = fmaxf(a0[j], a1[j]);
            }
            float4v av;
            #pragma unroll
            for (int j = 0; j < 4; ++j) {
                float mn = fmaxf(m[j], zm[j]);
                #pragma unroll
                for (int mask = 1; mask < 16; mask <<= 1)
                    mn = fmaxf(mn, __shfl_xor(mn, mask));
                const float al = exp2_fast(m[j] - mn);
                m[j] = mn; Zp[j] *= al; av[j] = al;
            }
            e0 *= av; e1 *= av; e2 *= av; e3 *= av;
            #pragma unroll
            for (int j = 0; j < 4; ++j) {
                const float p0 = exp2_fast(a0[j] - m[j]);
                const float p1 = exp2_fast(a1[j] - m[j]);
                Zp[j] += p0 + p1;
                ((uint32_t*)pbufP)[(wave*16 + quad*4 + j)*20 + col] = cvt_pk_bf16(p0, p1);
            }
        }

        // ---- GEMM2: emb += P . CB (pbuf wave-private; cbT swizzled reads) ----
        const short8 pa = *(const short8*)&pbufP[(wave*16 + col)*40 + quad*8];
        const int ts = (quad ^ (col & 3)) * 8;   // swizzled 16B slot within row
        const short8 bt0 = *(const short8*)&cbT[( 0 + col)*32 + ts];
        const short8 bt1 = *(const short8*)&cbT[(16 + col)*32 + ts];
        const short8 bt2 = *(const short8*)&cbT[(32 + col)*32 + ts];
        const short8 bt3 = *(const short8*)&cbT[(48 + col)*32 + ts];
        e0 = __builtin_amdgcn_mfma_f32_16x16x32_bf16(pa, bt0, e0, 0,0,0);
        e1 = __builtin_amdgcn_mfma_f32_16x16x32_bf16(pa, bt1, e1, 0,0,0);
        e2 = __builtin_amdgcn_mfma_f32_16x16x32_bf16(pa, bt2, e2, 0,0,0);
        e3 = __builtin_amdgcn_mfma_f32_16x16x32_bf16(pa, bt3, e3, 0,0,0);

        __syncthreads();   // drains vmcnt (next-tile DMA done) + lgkm; buffers swap-safe
    };

    for (int blk = 0; blk < 32; blk += 2) {
        body(blk,     IC<0>{});
        body(blk + 1, IC<TILE_B>{});
    }

    // ---- epilogue: reduce Z, merge top-2, f64 refine near-ties, write ----
    #pragma unroll
    for (int mask = 1; mask < 16; mask <<= 1) {
        #pragma unroll
        for (int j = 0; j < 4; ++j) Zp[j] += __shfl_xor(Zp[j], mask);
    }
    #pragma unroll
    for (int mask = 1; mask < 16; mask <<= 1) {
        #pragma unroll
        for (int j = 0; j < 4; ++j) {
            const float ozt = __shfl_xor(zt[j], mask);
            const float ozs = __shfl_xor(zs[j], mask);
            const int   okt = __shfl_xor(kt[j], mask);
            const int   oks = __shfl_xor(ks[j], mask);
            const bool mf = (zt[j] > ozt) || (zt[j] == ozt && kt[j] < okt);
            const float w1 = mf ? zt[j] : ozt;  const int wk1 = mf ? kt[j] : okt;
            const float l1 = mf ? ozt : zt[j];  const int lk1 = mf ? okt : kt[j];
            const float w2 = mf ? zs[j] : ozs;  const int wk2 = mf ? ks[j] : oks;
            const bool s1 = (l1 > w2) || (l1 == w2 && lk1 < wk2);
            zt[j] = w1; kt[j] = wk1;
            zs[j] = s1 ? l1 : w2; ks[j] = s1 ? lk1 : wk2;
        }
    }
    // exact f64 refinement for near-ties (split-bf16 dist err ~1e-6; z'-gap thr 0.015*invT
    // == dist gap ~1.04e-2, matching the proven 1e-2 margin; const shift cancels in gap)
    if (col == 0) {
        #pragma unroll
        for (int j = 0; j < 4; ++j) {
            if (zt[j] - zs[j] < 0.015f * invT) {
                const int t = quad*4 + j;
                const int row = rowbase + (t >> 1) + ((t & 1) << 16);
                const float* xr = x + (size_t)row * DIM;
                const float* cA = cb + (size_t)kt[j] * DIM;
                const float* cB = cb + (size_t)ks[j] * DIM;
                double dA = 0.0, dB = 0.0;     // ||c||^2 - 2 x.c (||x||^2 cancels)
                for (int d = 0; d < DIM; ++d) {
                    const double xv = (double)xr[d];
                    const double av2 = (double)cA[d], bv = (double)cB[d];
                    dA = fma(av2, av2, dA); dA = fma(-2.0*xv, av2, dA);
                    dB = fma(bv,  bv,  dB); dB = fma(-2.0*xv, bv,  dB);
                }
                if (dB < dA || (dB == dA && ks[j] < kt[j])) kt[j] = ks[j];
            }
        }
    }
    #pragma unroll
    for (int j = 0; j < 4; ++j) {
        const int t = quad*4 + j;
        const int row = rowbase + (t >> 1) + ((t & 1) << 16);
        const float rZ = __builtin_amdgcn_rcpf(Zp[j]);
        out_emb[(size_t)row * DIM +      col] = e0[j] * rZ;
        out_emb[(size_t)row * DIM + 16 + col] = e1[j] * rZ;
        out_emb[(size_t)row * DIM + 32 + col] = e2[j] * rZ;
        out_emb[(size_t)row * DIM + 48 + col] = e3[j] * rZ;
        if (col == 0) out_ids[row] = (float)kt[j];
    }
}

__global__ __launch_bounds__(512) __attribute__((amdgpu_waves_per_eu(4, 4)))
void quant_kernel(
    const float* __restrict__ x, const uint16_t* __restrict__ img,
    const float* __restrict__ cb, const float* __restrict__ temp,
    float* __restrict__ out_emb, float* __restrict__ out_ids)
{
    __shared__ __align__(16) char smem[36864];
    const float invT = 1.0f / temp[0];
    if (invT == 1.0f) quant_body<true >(x, img, cb, invT, out_emb, out_ids, smem);
    else              quant_body<false>(x, img, cb, invT, out_emb, out_ids, smem);
}

extern "C" void kernel_launch(void* const* d_in, const int* in_sizes, int n_in,
                              void* d_out, int out_size, void* d_ws, size_t ws_size,
                              hipStream_t stream) {
    const float* x    = (const float*)d_in[0];
    const float* cb   = (const float*)d_in[1];
    const float* temp = (const float*)d_in[2];
    uint16_t* img     = (uint16_t*)d_ws;                  // 32 tiles x 13312 B = 416 KiB
    float* out_emb    = (float*)d_out;
    float* out_ids    = (float*)d_out + (size_t)N_ROWS * DIM;

    cbimg_kernel<<<32, 256, 0, stream>>>(cb, temp, img);
    quant_kernel<<<N_ROWS / 128, 512, 0, stream>>>(x, img, cb, temp, out_emb, out_ids);
}